// Round 3
// baseline (289.279 us; speedup 1.0000x reference)
//
#include <hip/hip_runtime.h>
#include <math.h>

#define NB 16
#define NE 5
#define LL 128
#define HH 768
#define NK 21
#define NCLS 3
#define NN (NB*NE)   // 80

typedef float f32x4 __attribute__((ext_vector_type(4)));
typedef short s16x8 __attribute__((ext_vector_type(8)));

__device__ __forceinline__ short bf16rne(float f) {
    union { float f; unsigned u; } c; c.f = f;
    unsigned u = c.u;
    unsigned r = (u + 0x7FFFu + ((u >> 16) & 1u)) >> 16;
    return (short)r;
}
__device__ __forceinline__ float red16(float v) {
    v += __shfl_xor(v, 1, 64); v += __shfl_xor(v, 2, 64);
    v += __shfl_xor(v, 4, 64); v += __shfl_xor(v, 8, 64);
    return v;
}

// ---------------- K0: normalize + bf16 + MFMA-fragment swizzle ----------------
// per doc: 24 K-steps x 512 units x 8 bf16; unit u = (row>>4)*64 + kseg*16 + (row&15)
__global__ __launch_bounds__(256) void k_prep(const float* __restrict__ hid,
                                              short* __restrict__ hswz) {
    const int n = blockIdx.x;
    const int tid = threadIdx.x, l = tid & 63, w = tid >> 6;
    __shared__ float sInv[LL];
    for (int rr = 0; rr < 32; ++rr) {
        const int row = w * 32 + rr;
        const float4* rp = reinterpret_cast<const float4*>(hid + ((size_t)n * LL + row) * HH);
        float4 a = rp[l], b = rp[l + 64], c = rp[l + 128];
        float ss = a.x*a.x + a.y*a.y + a.z*a.z + a.w*a.w
                 + b.x*b.x + b.y*b.y + b.z*b.z + b.w*b.w
                 + c.x*c.x + c.y*c.y + c.z*c.z + c.w*c.w;
        #pragma unroll
        for (int o = 32; o > 0; o >>= 1) ss += __shfl_xor(ss, o, 64);
        if (l == 0) sInv[row] = 1.0f / fmaxf(sqrtf(ss), 1e-12f);
    }
    __syncthreads();
    const float* base = hid + (size_t)n * LL * HH;
    s16x8* dst = reinterpret_cast<s16x8*>(hswz) + (size_t)n * 12288;
    for (int ui = tid; ui < 12288; ui += 256) {
        const int s = ui >> 9, r = ui & 511;
        const int row = ((r >> 6) << 4) | (r & 15);
        const int kb = s * 32 + ((r >> 4) & 3) * 8;
        const float4* p = reinterpret_cast<const float4*>(base + (size_t)row * HH + kb);
        float4 v0 = p[0], v1 = p[1];
        const float inv = sInv[row];
        s16x8 h;
        h[0] = bf16rne(v0.x * inv); h[1] = bf16rne(v0.y * inv);
        h[2] = bf16rne(v0.z * inv); h[3] = bf16rne(v0.w * inv);
        h[4] = bf16rne(v1.x * inv); h[5] = bf16rne(v1.y * inv);
        h[6] = bf16rne(v1.z * inv); h[7] = bf16rne(v1.w * inv);
        dst[ui] = h;
    }
}

// ------- K2: MFMA sim + chain kernel-pool + att softmax + denoise + sel -------
__global__ __launch_bounds__(256, 2) void k_simpool(
    const short* __restrict__ hswz, const float* __restrict__ hid,
    const float* __restrict__ mask_text, const float* __restrict__ mask_claim,
    const float* __restrict__ mask_evidence,
    const float* __restrict__ W_att, const float* __restrict__ b_att,
    const float* __restrict__ W_sel, const float* __restrict__ b_sel,
    float* __restrict__ denoi, float* __restrict__ dsel)
{
    const int bid = blockIdx.x;
    const int b = bid & 15, pair = bid >> 4;
    const int e = pair / NE, ep = pair - e * NE;
    const int nq = b * NE + e, nd = b * NE + ep;
    const bool diag = (e == ep);
    const int tid = threadIdx.x, lane = tid & 63, w = tid >> 6;
    const int lx = lane & 15, lg = lane >> 4;

    __shared__ s16x8 sB[2][512];          // 16 KB double-buffered B tile
    __shared__ float sPoolA[NK * LL];     // 10.5 KB
    __shared__ float sPoolS[NK * LL];     // 10.5 KB
    __shared__ float sMT[LL], sMEd[LL], sMEq[LL], sMCq[LL], sAtt[LL], sSelRow[LL];

    if (tid < LL) {
        sMT[tid]  = mask_text[nd * LL + tid];
        sMEd[tid] = mask_evidence[nd * LL + tid];
        sMEq[tid] = mask_evidence[nq * LL + tid];
        sMCq[tid] = mask_claim[nq * LL + tid];
    }

    const s16x8* gA = reinterpret_cast<const s16x8*>(hswz) + (size_t)nq * 12288;
    const s16x8* gB = reinterpret_cast<const s16x8*>(hswz) + (size_t)nd * 12288;

    // prologue: stage B step 0, load A frags step 0
    sB[0][tid] = gB[tid];
    sB[0][tid + 256] = gB[tid + 256];
    s16x8 aC0 = gA[(w * 2 + 0) * 64 + lane];
    s16x8 aC1 = gA[(w * 2 + 1) * 64 + lane];

    f32x4 acc[2][8];
    #pragma unroll
    for (int mi = 0; mi < 2; ++mi)
        #pragma unroll
        for (int nj = 0; nj < 8; ++nj) acc[mi][nj] = (f32x4){0.f, 0.f, 0.f, 0.f};

    __syncthreads();

    for (int s = 0; s < 24; ++s) {
        const int cur = s & 1;
        s16x8 n0, n1, aN0, aN1;
        if (s < 23) {
            n0  = gB[(s + 1) * 512 + tid];
            n1  = gB[(s + 1) * 512 + 256 + tid];
            aN0 = gA[(s + 1) * 512 + (w * 2 + 0) * 64 + lane];
            aN1 = gA[(s + 1) * 512 + (w * 2 + 1) * 64 + lane];
        }
        #pragma unroll
        for (int nj = 0; nj < 8; ++nj) {
            s16x8 bf = sB[cur][nj * 64 + lane];
            acc[0][nj] = __builtin_amdgcn_mfma_f32_16x16x32_bf16(aC0, bf, acc[0][nj], 0, 0, 0);
            acc[1][nj] = __builtin_amdgcn_mfma_f32_16x16x32_bf16(aC1, bf, acc[1][nj], 0, 0, 0);
        }
        if (s < 23) {
            sB[1 - cur][tid] = n0;
            sB[1 - cur][tid + 256] = n1;
            aC0 = aN0; aC1 = aN1;
        }
        __syncthreads();
    }

    // ---- epilogue: chain-based kernel pooling ----
    // g_k = g_{k-1} * e^{-10 s} * e^{11-k}  =>  pool_k = D_k * sum_j u_j, D_k = e^{9.5(k-1)-0.5(k-1)^2}
    // u carries a 2^32 scale (folded into P); CKs[k] = D_k * 2^-32.
    const float CKs[21] = { 0.f,
        2.3283064e-10f, 1.8866462e-6f, 5.6240094e-3f, 6.1674791f, 2488.139f,
        3.6927288e5f, 2.0161595e7f, 4.0495649e8f, 2.9922461e9f, 8.1337695e9f,
        8.1337695e9f, 2.9922461e9f, 4.0495649e8f, 2.0161595e7f, 3.6927288e5f,
        2488.139f, 6.1674791f, 5.6240094e-3f, 1.8866462e-6f, 2.3283064e-10f };
    float mtv[8], mev[8];
    #pragma unroll
    for (int nj = 0; nj < 8; ++nj) {
        mtv[nj] = sMT[nj * 16 + lx];
        mev[nj] = sMEd[nj * 16 + lx];
    }
    #pragma unroll
    for (int mi = 0; mi < 2; ++mi) {
        #pragma unroll
        for (int r = 0; r < 4; ++r) {
            const int row = w * 32 + mi * 16 + lg * 4 + r;
            float sv[8];
            #pragma unroll
            for (int nj = 0; nj < 8; ++nj) sv[nj] = acc[mi][nj][r];
            // k = 0 (mu=1, sigma=0.001) brute force
            float pa = 0.f, pse = 0.f;
            #pragma unroll
            for (int nj = 0; nj < 8; ++nj) {
                float d = sv[nj] - 1.0f;
                float g = exp2f(d * d * -721347.52f);
                pa += mtv[nj] * g;
                pse += mev[nj] * g;
            }
            pa = red16(pa);
            if (lx == 0) sPoolA[row] = pa;
            if (diag) { pse = red16(pse); if (lx == 0) sPoolS[row] = pse; }
            // chain k = 1..20
            float u[8], u2[8], t[8];
            #pragma unroll
            for (int nj = 0; nj < 8; ++nj) {
                float d = sv[nj] - 0.95f;
                float P = exp2f(fmaf(d * d, -72.134752f, 32.0f));
                t[nj] = exp2f(sv[nj] * -14.4269504f);
                u[nj] = mtv[nj] * P;
                u2[nj] = mev[nj] * P;
            }
            #pragma unroll
            for (int k = 1; k <= 20; ++k) {
                if (k > 1) {
                    #pragma unroll
                    for (int nj = 0; nj < 8; ++nj) {
                        u[nj] *= t[nj];
                        if (diag) u2[nj] *= t[nj];
                    }
                }
                float su = ((u[0]+u[1])+(u[2]+u[3])) + ((u[4]+u[5])+(u[6]+u[7]));
                su = red16(su);
                if (lx == 0) sPoolA[k * LL + row] = su * CKs[k];
                if (diag) {
                    float s2 = ((u2[0]+u2[1])+(u2[2]+u2[3])) + ((u2[4]+u2[5])+(u2[6]+u2[7]));
                    s2 = red16(s2);
                    if (lx == 0) sPoolS[k * LL + row] = s2 * CKs[k];
                }
            }
        }
    }
    __syncthreads();

    // ---- logits (ln = log2 * ln2) ----
    if (tid < LL) {
        const int row = tid;
        float lgt = b_att[0];
        #pragma unroll
        for (int k = 0; k < NK; ++k)
            lgt += (W_att[k] * 0.69314718f) * log2f(fmaxf(sPoolA[k * LL + row], 1e-10f));
        sAtt[row] = (sMEq[row] == 0.0f) ? -10000.0f : lgt;
        if (diag) {
            float rv = 0.f;
            #pragma unroll
            for (int k = 0; k < NK; ++k)
                rv += (W_sel[k] * 0.69314718f) * log2f(fmaxf(sPoolS[k * LL + row], 1e-10f));
            sSelRow[row] = sMCq[row] * rv;
        }
    }
    __syncthreads();

    // ---- softmax over q (wave 0) ----
    if (tid < 64) {
        float a0 = sAtt[tid], a1 = sAtt[tid + 64];
        float m = fmaxf(a0, a1);
        #pragma unroll
        for (int o = 32; o > 0; o >>= 1) m = fmaxf(m, __shfl_xor(m, o, 64));
        float e0 = __expf(a0 - m), e1 = __expf(a1 - m);
        float ssum = e0 + e1;
        #pragma unroll
        for (int o = 32; o > 0; o >>= 1) ssum += __shfl_xor(ssum, o, 64);
        float inv = 1.0f / ssum;
        sAtt[tid] = e0 * inv; sAtt[tid + 64] = e1 * inv;
    }
    __syncthreads();

    // ---- denoise: att^T x hid[nq] (raw fp32) ----
    const float* hq = hid + (size_t)nq * LL * HH;
    for (int h = tid; h < HH; h += 256) {
        float a = 0.f;
        for (int q = 0; q < LL; ++q) a += sAtt[q] * hq[(size_t)q * HH + h];
        denoi[((size_t)ep * NN + nq) * HH + h] = a;
    }

    // ---- sel logit (diag blocks only) ----
    if (diag && tid == 0) {
        float su = 0.f, ms = 0.f;
        for (int q = 0; q < LL; ++q) { su += sSelRow[q]; ms += sMCq[q]; }
        dsel[nq] = b_sel[0] + 0.01f * su / (ms + 1e-10f);
    }
}

// ---------------- K5a: transpose W1 -> W1T[128][1536] ----------------
__global__ __launch_bounds__(256) void k_w1t(const float* __restrict__ W1,
                                             float* __restrict__ w1t) {
    int o = blockIdx.x * 256 + threadIdx.x;
    int j = o / 1536, t = o - j * 1536;
    w1t[o] = W1[(size_t)t * 128 + j];
}

// ---------------- K5b: GAT gate — one wave per (j-pair, 8 p's) --------------
__global__ __launch_bounds__(256) void k_gat2(
    const float* __restrict__ inputs, const float* __restrict__ denoise,
    const float* __restrict__ w1t, const float* __restrict__ b1,
    const float* __restrict__ W2, float* __restrict__ part)
{
    int wid = blockIdx.x * 4 + (threadIdx.x >> 6);
    int l = threadIdx.x & 63;
    int jp = wid & 63;
    int po = wid >> 6;
    int j0 = jp * 2, j1 = j0 + 1;
    int pb = po * 8;

    float a0[8], a1[8];
    #pragma unroll
    for (int u = 0; u < 8; ++u) { a0[u] = 0.f; a1[u] = 0.f; }
    const float* wc0 = w1t + (size_t)j0 * 1536;
    const float* wc1 = w1t + (size_t)j1 * 1536;
    const float* fin[8]; const float* fde[8];
    #pragma unroll
    for (int u = 0; u < 8; ++u) {
        int p = pb + u;
        int i = p / NN; int n2 = p - i * NN; int bb = n2 / NE;
        fin[u] = inputs + ((size_t)bb * NE + i) * HH;
        fde[u] = denoise + (size_t)p * HH;
    }
    for (int it = 0; it < 24; ++it) {
        int t = it * 64 + l;
        float wv0 = wc0[t], wv1 = wc1[t];
        const bool isde = (it >= 12);
        int t2 = isde ? (t - HH) : t;
        #pragma unroll
        for (int u = 0; u < 8; ++u) {
            float fv = isde ? fde[u][t2] : fin[u][t2];
            a0[u] += fv * wv0;
            a1[u] += fv * wv1;
        }
    }
    #pragma unroll
    for (int u = 0; u < 8; ++u) {
        #pragma unroll
        for (int o = 32; o > 0; o >>= 1) {
            a0[u] += __shfl_xor(a0[u], o, 64);
            a1[u] += __shfl_xor(a1[u], o, 64);
        }
    }
    float bb0 = b1[j0], bb1 = b1[j1], w20 = W2[j0], w21 = W2[j1];
    if (l == 0) {
        #pragma unroll
        for (int u = 0; u < 8; ++u) {
            float v = fmaxf(a0[u] + bb0, 0.f) * w20 + fmaxf(a1[u] + bb1, 0.f) * w21;
            part[(size_t)(pb + u) * 64 + jp] = v;
        }
    }
}

// ---------------- K5c: deterministic reduce of part -> gsc ----------------
__global__ __launch_bounds__(256) void k_gatred(const float* __restrict__ part,
                                                float* __restrict__ gsc) {
    int p = blockIdx.x * 256 + threadIdx.x;
    if (p < NE * NN) {
        float s = 0.f;
        for (int jp = 0; jp < 64; ++jp) s += part[(size_t)p * 64 + jp];
        gsc[p] = s;   // b2 omitted: uniform shift, softmax-invariant
    }
}

// ---------------- K6: final combine, softmaxes, output ----------------
__global__ __launch_bounds__(256) void k_final(
    const float* __restrict__ inputs, const float* __restrict__ denoise,
    const float* __restrict__ gsc, const float* __restrict__ dsel,
    const float* __restrict__ inf_W, const float* __restrict__ inf_b,
    float* __restrict__ out)
{
    int b = blockIdx.x;
    int tid = threadIdx.x;
    __shared__ float sp[NE];
    __shared__ float wde[NE][NE];
    __shared__ float logi[NCLS];
    __shared__ float accp[NCLS];
    __shared__ float red[4];
    if (tid == 0) {
        float m = -1e30f;
        for (int e2 = 0; e2 < NE; ++e2) m = fmaxf(m, dsel[b * NE + e2]);
        float s = 0.f;
        for (int e2 = 0; e2 < NE; ++e2) { float v = __expf(dsel[b * NE + e2] - m); sp[e2] = v; s += v; }
        for (int e2 = 0; e2 < NE; ++e2) sp[e2] /= s;
        for (int i = 0; i < NE; ++i) {
            float mm = -1e30f;
            for (int e2 = 0; e2 < NE; ++e2) mm = fmaxf(mm, gsc[i * NN + b * NE + e2]);
            float ss = 0.f;
            for (int e2 = 0; e2 < NE; ++e2) { float v = __expf(gsc[i * NN + b * NE + e2] - mm); wde[i][e2] = v; ss += v; }
            for (int e2 = 0; e2 < NE; ++e2) wde[i][e2] /= ss;
        }
        for (int c = 0; c < NCLS; ++c) accp[c] = 0.f;
    }
    __syncthreads();
    for (int i = 0; i < NE; ++i) {
        float part[NCLS] = {0.f, 0.f, 0.f};
        for (int t = tid; t < 2 * HH; t += 256) {
            float f;
            if (t < HH) f = inputs[((size_t)b * NE + i) * HH + t];
            else {
                int h = t - HH;
                float a = 0.f;
                for (int e2 = 0; e2 < NE; ++e2)
                    a += wde[i][e2] * denoise[((size_t)i * NN + b * NE + e2) * HH + h];
                f = a;
            }
            #pragma unroll
            for (int c = 0; c < NCLS; ++c) part[c] += f * inf_W[(size_t)t * NCLS + c];
        }
        for (int c = 0; c < NCLS; ++c) {
            float v = part[c];
            #pragma unroll
            for (int o = 32; o > 0; o >>= 1) v += __shfl_down(v, o, 64);
            if ((tid & 63) == 0) red[tid >> 6] = v;
            __syncthreads();
            if (tid == 0) logi[c] = red[0] + red[1] + red[2] + red[3] + inf_b[c];
            __syncthreads();
        }
        if (tid == 0) {
            float mm = fmaxf(fmaxf(logi[0], logi[1]), logi[2]);
            float e0 = __expf(logi[0] - mm), e1 = __expf(logi[1] - mm), e2 = __expf(logi[2] - mm);
            float ss = e0 + e1 + e2;
            accp[0] += sp[i] * (e0 / ss);
            accp[1] += sp[i] * (e1 / ss);
            accp[2] += sp[i] * (e2 / ss);
        }
        __syncthreads();
    }
    if (tid < NCLS) out[b * NCLS + tid] = logf(accp[tid]);
}

extern "C" void kernel_launch(void* const* d_in, const int* in_sizes, int n_in,
                              void* d_out, int out_size, void* d_ws, size_t ws_size,
                              hipStream_t stream) {
    (void)in_sizes; (void)n_in; (void)out_size; (void)ws_size;
    const float* hid           = (const float*)d_in[0];
    const float* inputs        = (const float*)d_in[1];
    const float* mask_text     = (const float*)d_in[2];
    const float* mask_claim    = (const float*)d_in[3];
    const float* mask_evidence = (const float*)d_in[4];
    const float* W_att  = (const float*)d_in[5];
    const float* b_att  = (const float*)d_in[6];
    const float* W_sel  = (const float*)d_in[7];
    const float* b_sel  = (const float*)d_in[8];
    const float* gat_W1 = (const float*)d_in[9];
    const float* gat_b1 = (const float*)d_in[10];
    const float* gat_W2 = (const float*)d_in[11];
    const float* gat_b2 = (const float*)d_in[12];
    const float* inf_W  = (const float*)d_in[13];
    const float* inf_b  = (const float*)d_in[14];
    (void)gat_b2;

    short* hswz  = (short*)d_ws;                              // 80*12288*8 bf16 = 15,728,640 B
    float* denoi = (float*)((char*)d_ws + 15728640);          // 307,200 f
    float* dsel  = denoi + 307200;                            // 80
    float* gsc   = dsel + 80;                                 // 400
    float* w1t   = gsc + 400;                                 // 196,608
    float* part  = w1t + 196608;                              // 25,600

    k_prep<<<NN, 256, 0, stream>>>(hid, hswz);
    k_w1t<<<(2 * HH * 128) / 256, 256, 0, stream>>>(gat_W1, w1t);
    k_simpool<<<NB * 25, 256, 0, stream>>>(hswz, hid, mask_text, mask_claim, mask_evidence,
                                           W_att, b_att, W_sel, b_sel, denoi, dsel);
    k_gat2<<<800, 256, 0, stream>>>(inputs, denoi, w1t, gat_b1, gat_W2, part);
    k_gatred<<<2, 256, 0, stream>>>(part, gsc);
    k_final<<<NB, 256, 0, stream>>>(inputs, denoi, gsc, dsel, inf_W, inf_b, (float*)d_out);
}

// Round 4
// 194.031 us; speedup vs baseline: 1.4909x; 1.4909x over previous
//
#include <hip/hip_runtime.h>
#include <math.h>

#define NB 16
#define NE 5
#define LL 128
#define HH 768
#define NK 21
#define NCLS 3
#define NN (NB*NE)   // 80

typedef float f32x4 __attribute__((ext_vector_type(4)));
typedef short s16x8 __attribute__((ext_vector_type(8)));

__device__ __forceinline__ short bf16rne(float f) {
    union { float f; unsigned u; } c; c.f = f;
    unsigned u = c.u;
    unsigned r = (u + 0x7FFFu + ((u >> 16) & 1u)) >> 16;
    return (short)r;
}
__device__ __forceinline__ float red16(float v) {
    v += __shfl_xor(v, 1, 64); v += __shfl_xor(v, 2, 64);
    v += __shfl_xor(v, 4, 64); v += __shfl_xor(v, 8, 64);
    return v;
}

// ---------------- K0: normalize + bf16 + MFMA-fragment swizzle ----------------
__global__ __launch_bounds__(256) void k_prep(const float* __restrict__ hid,
                                              short* __restrict__ hswz) {
    const int n = blockIdx.x;
    const int tid = threadIdx.x, l = tid & 63, w = tid >> 6;
    __shared__ float sInv[LL];
    for (int rr = 0; rr < 32; ++rr) {
        const int row = w * 32 + rr;
        const float4* rp = reinterpret_cast<const float4*>(hid + ((size_t)n * LL + row) * HH);
        float4 a = rp[l], b = rp[l + 64], c = rp[l + 128];
        float ss = a.x*a.x + a.y*a.y + a.z*a.z + a.w*a.w
                 + b.x*b.x + b.y*b.y + b.z*b.z + b.w*b.w
                 + c.x*c.x + c.y*c.y + c.z*c.z + c.w*c.w;
        #pragma unroll
        for (int o = 32; o > 0; o >>= 1) ss += __shfl_xor(ss, o, 64);
        if (l == 0) sInv[row] = 1.0f / fmaxf(sqrtf(ss), 1e-12f);
    }
    __syncthreads();
    const float* base = hid + (size_t)n * LL * HH;
    s16x8* dst = reinterpret_cast<s16x8*>(hswz) + (size_t)n * 12288;
    for (int ui = tid; ui < 12288; ui += 256) {
        const int s = ui >> 9, r = ui & 511;
        const int row = ((r >> 6) << 4) | (r & 15);
        const int kb = s * 32 + ((r >> 4) & 3) * 8;
        const float4* p = reinterpret_cast<const float4*>(base + (size_t)row * HH + kb);
        float4 v0 = p[0], v1 = p[1];
        const float inv = sInv[row];
        s16x8 h;
        h[0] = bf16rne(v0.x * inv); h[1] = bf16rne(v0.y * inv);
        h[2] = bf16rne(v0.z * inv); h[3] = bf16rne(v0.w * inv);
        h[4] = bf16rne(v1.x * inv); h[5] = bf16rne(v1.y * inv);
        h[6] = bf16rne(v1.z * inv); h[7] = bf16rne(v1.w * inv);
        dst[ui] = h;
    }
}

// -------- epilogue row: chain kernel-pool -> logit accum, ALL named scalars --
__device__ __forceinline__ void epi_row(
    float s0, float s1, float s2, float s3, float s4, float s5, float s6, float s7,
    float mt0, float mt1, float mt2, float mt3, float mt4, float mt5, float mt6, float mt7,
    float me0, float me1, float me2, float me3, float me4, float me5, float me6, float me7,
    bool diag, float bAtt,
    const float* __restrict__ sWA, const float* __restrict__ sWS,
    const float* __restrict__ sCK,
    float* __restrict__ sAtt, float* __restrict__ sSelRow,
    const float* __restrict__ sMEq, const float* __restrict__ sMCq,
    int row, int lx)
{
    // k = 0: mu = 1, sigma = 0.001
    float pa = 0.f, ps = 0.f;
#define PK0(S, MT, ME) { float d_ = (S) - 1.0f; float g_ = exp2f(d_ * d_ * -721347.52f); \
                         pa += (MT) * g_; ps += (ME) * g_; }
    PK0(s0, mt0, me0) PK0(s1, mt1, me1) PK0(s2, mt2, me2) PK0(s3, mt3, me3)
    PK0(s4, mt4, me4) PK0(s5, mt5, me5) PK0(s6, mt6, me6) PK0(s7, mt7, me7)
#undef PK0
    pa = red16(pa);
    float lgt = fmaf(sWA[0], log2f(fmaxf(pa, 1e-10f)), bAtt);
    float rv = 0.f;
    if (diag) { ps = red16(ps); rv = sWS[0] * log2f(fmaxf(ps, 1e-10f)); }

    // chain setup: P = 2^32 * exp(-50(s-0.95)^2), t = exp(-10 s)
    float u0,u1,u2,u3,u4,u5,u6,u7, v0,v1,v2,v3,v4,v5,v6,v7, t0,t1,t2,t3,t4,t5,t6,t7;
#define PKC(S, MT, ME, U, V, T) { float d_ = (S) - 0.95f; \
        float P_ = exp2f(fmaf(d_ * d_, -72.134752f, 32.0f)); \
        (T) = exp2f((S) * -14.4269504f); (U) = (MT) * P_; (V) = (ME) * P_; }
    PKC(s0, mt0, me0, u0, v0, t0) PKC(s1, mt1, me1, u1, v1, t1)
    PKC(s2, mt2, me2, u2, v2, t2) PKC(s3, mt3, me3, u3, v3, t3)
    PKC(s4, mt4, me4, u4, v4, t4) PKC(s5, mt5, me5, u5, v5, t5)
    PKC(s6, mt6, me6, u6, v6, t6) PKC(s7, mt7, me7, u7, v7, t7)
#undef PKC
    {
        float su = ((u0 + u1) + (u2 + u3)) + ((u4 + u5) + (u6 + u7));
        su = red16(su);
        lgt = fmaf(sWA[1], log2f(fmaxf(su * sCK[1], 1e-10f)), lgt);
        if (diag) {
            float sv = ((v0 + v1) + (v2 + v3)) + ((v4 + v5) + (v6 + v7));
            sv = red16(sv);
            rv = fmaf(sWS[1], log2f(fmaxf(sv * sCK[1], 1e-10f)), rv);
        }
    }
    for (int k = 2; k <= 20; ++k) {
        u0 *= t0; u1 *= t1; u2 *= t2; u3 *= t3;
        u4 *= t4; u5 *= t5; u6 *= t6; u7 *= t7;
        float su = ((u0 + u1) + (u2 + u3)) + ((u4 + u5) + (u6 + u7));
        su = red16(su);
        lgt = fmaf(sWA[k], log2f(fmaxf(su * sCK[k], 1e-10f)), lgt);
        if (diag) {
            v0 *= t0; v1 *= t1; v2 *= t2; v3 *= t3;
            v4 *= t4; v5 *= t5; v6 *= t6; v7 *= t7;
            float sv = ((v0 + v1) + (v2 + v3)) + ((v4 + v5) + (v6 + v7));
            sv = red16(sv);
            rv = fmaf(sWS[k], log2f(fmaxf(sv * sCK[k], 1e-10f)), rv);
        }
    }
    if (lx == 0) {
        sAtt[row] = (sMEq[row] == 0.0f) ? -10000.0f : lgt;
        if (diag) sSelRow[row] = sMCq[row] * rv;
    }
}

// ------- K2: MFMA sim + in-register pooled logits + softmax + denoise + sel --
__global__ __launch_bounds__(256, 3) void k_simpool(
    const short* __restrict__ hswz, const float* __restrict__ hid,
    const float* __restrict__ mask_text, const float* __restrict__ mask_claim,
    const float* __restrict__ mask_evidence,
    const float* __restrict__ W_att, const float* __restrict__ b_att,
    const float* __restrict__ W_sel, const float* __restrict__ b_sel,
    float* __restrict__ denoi, float* __restrict__ dsel)
{
    const int bid = blockIdx.x;
    const int b = bid & 15, pair = bid >> 4;
    const int e = pair / NE, ep = pair - e * NE;
    const int nq = b * NE + e, nd = b * NE + ep;
    const bool diag = (e == ep);
    const int tid = threadIdx.x, lane = tid & 63, w = tid >> 6;
    const int lx = lane & 15, lg = lane >> 4;

    __shared__ s16x8 sB[2][512];                       // 16 KB
    __shared__ float sMT[LL], sMEd[LL], sMEq[LL], sMCq[LL];
    __shared__ float sAtt[LL], sSelRow[LL];
    __shared__ float sWA[NK], sWS[NK], sCK[NK];

    if (tid < LL) {
        sMT[tid]  = mask_text[nd * LL + tid];
        sMEd[tid] = mask_evidence[nd * LL + tid];
        sMEq[tid] = mask_evidence[nq * LL + tid];
        sMCq[tid] = mask_claim[nq * LL + tid];
    } else if (tid >= 128 && tid < 128 + NK) {
        sWA[tid - 128] = W_att[tid - 128] * 0.69314718f;
    } else if (tid >= 160 && tid < 160 + NK) {
        sWS[tid - 160] = W_sel[tid - 160] * 0.69314718f;
    } else if (tid >= 192 && tid < 212) {
        const int k = tid - 191;                        // 1..20
        const float kk = (float)(k - 1);
        sCK[k] = exp2f(fmaf(kk, 13.7056029f, fmaf(kk * kk, -0.72134752f, -32.0f)));
    }

    const s16x8* gA = reinterpret_cast<const s16x8*>(hswz) + (size_t)nq * 12288;
    const s16x8* gB = reinterpret_cast<const s16x8*>(hswz) + (size_t)nd * 12288;

    sB[0][tid] = gB[tid];
    sB[0][tid + 256] = gB[tid + 256];
    s16x8 aC0 = gA[(w * 2 + 0) * 64 + lane];
    s16x8 aC1 = gA[(w * 2 + 1) * 64 + lane];

    f32x4 acc[2][8];
    #pragma unroll
    for (int mi = 0; mi < 2; ++mi)
        #pragma unroll
        for (int nj = 0; nj < 8; ++nj) acc[mi][nj] = (f32x4){0.f, 0.f, 0.f, 0.f};

    __syncthreads();

    for (int s = 0; s < 24; ++s) {
        const int cur = s & 1;
        s16x8 n0, n1, aN0, aN1;
        if (s < 23) {
            n0  = gB[(s + 1) * 512 + tid];
            n1  = gB[(s + 1) * 512 + 256 + tid];
            aN0 = gA[(s + 1) * 512 + (w * 2 + 0) * 64 + lane];
            aN1 = gA[(s + 1) * 512 + (w * 2 + 1) * 64 + lane];
        }
        #pragma unroll
        for (int nj = 0; nj < 8; ++nj) {
            s16x8 bf = sB[cur][nj * 64 + lane];
            acc[0][nj] = __builtin_amdgcn_mfma_f32_16x16x32_bf16(aC0, bf, acc[0][nj], 0, 0, 0);
            acc[1][nj] = __builtin_amdgcn_mfma_f32_16x16x32_bf16(aC1, bf, acc[1][nj], 0, 0, 0);
        }
        if (s < 23) {
            sB[1 - cur][tid] = n0;
            sB[1 - cur][tid + 256] = n1;
            aC0 = aN0; aC1 = aN1;
        }
        __syncthreads();
    }

    // ---- epilogue: 8 rows/thread, all static ----
    const float bAtt = b_att[0];
    const float mt0 = sMT[lx],       mt1 = sMT[16 + lx],  mt2 = sMT[32 + lx],  mt3 = sMT[48 + lx];
    const float mt4 = sMT[64 + lx],  mt5 = sMT[80 + lx],  mt6 = sMT[96 + lx],  mt7 = sMT[112 + lx];
    float me0 = 0.f, me1 = 0.f, me2 = 0.f, me3 = 0.f, me4 = 0.f, me5 = 0.f, me6 = 0.f, me7 = 0.f;
    if (diag) {
        me0 = sMEd[lx];      me1 = sMEd[16 + lx]; me2 = sMEd[32 + lx];  me3 = sMEd[48 + lx];
        me4 = sMEd[64 + lx]; me5 = sMEd[80 + lx]; me6 = sMEd[96 + lx];  me7 = sMEd[112 + lx];
    }
    const int rb = w * 32 + lg * 4;
#define EPI(MI, R) epi_row(acc[MI][0][R], acc[MI][1][R], acc[MI][2][R], acc[MI][3][R], \
                           acc[MI][4][R], acc[MI][5][R], acc[MI][6][R], acc[MI][7][R], \
                           mt0, mt1, mt2, mt3, mt4, mt5, mt6, mt7, \
                           me0, me1, me2, me3, me4, me5, me6, me7, \
                           diag, bAtt, sWA, sWS, sCK, sAtt, sSelRow, sMEq, sMCq, \
                           rb + (MI) * 16 + (R), lx);
    EPI(0, 0) EPI(0, 1) EPI(0, 2) EPI(0, 3)
    EPI(1, 0) EPI(1, 1) EPI(1, 2) EPI(1, 3)
#undef EPI
    __syncthreads();

    // ---- softmax over q (wave 0) + dsel (wave 1) ----
    if (tid < 64) {
        float a0 = sAtt[tid], a1 = sAtt[tid + 64];
        float m = fmaxf(a0, a1);
        #pragma unroll
        for (int o = 32; o > 0; o >>= 1) m = fmaxf(m, __shfl_xor(m, o, 64));
        float e0 = __expf(a0 - m), e1 = __expf(a1 - m);
        float ssum = e0 + e1;
        #pragma unroll
        for (int o = 32; o > 0; o >>= 1) ssum += __shfl_xor(ssum, o, 64);
        float inv = 1.0f / ssum;
        sAtt[tid] = e0 * inv; sAtt[tid + 64] = e1 * inv;
    } else if (diag && tid < 128) {
        const int l2 = tid - 64;
        float su = sSelRow[l2] + sSelRow[l2 + 64];
        float ms = sMCq[l2] + sMCq[l2 + 64];
        #pragma unroll
        for (int o = 32; o > 0; o >>= 1) {
            su += __shfl_xor(su, o, 64);
            ms += __shfl_xor(ms, o, 64);
        }
        if (l2 == 0) dsel[nq] = b_sel[0] + 0.01f * su / (ms + 1e-10f);
    }
    __syncthreads();

    // ---- denoise: att^T x hid[nq] ----
    const float* hq = hid + (size_t)nq * LL * HH;
    for (int h = tid; h < HH; h += 256) {
        float a = 0.f;
        for (int q = 0; q < LL; ++q) a += sAtt[q] * hq[(size_t)q * HH + h];
        denoi[((size_t)ep * NN + nq) * HH + h] = a;
    }
}

// ---------------- K5a: transpose W1 -> W1T[128][1536] ----------------
__global__ __launch_bounds__(256) void k_w1t(const float* __restrict__ W1,
                                             float* __restrict__ w1t) {
    int o = blockIdx.x * 256 + threadIdx.x;
    int j = o / 1536, t = o - j * 1536;
    w1t[o] = W1[(size_t)t * 128 + j];
}

// ---------------- K5b: GAT gate — one wave per (j-pair, 8 p's) --------------
__global__ __launch_bounds__(256) void k_gat2(
    const float* __restrict__ inputs, const float* __restrict__ denoise,
    const float* __restrict__ w1t, const float* __restrict__ b1,
    const float* __restrict__ W2, float* __restrict__ part)
{
    int wid = blockIdx.x * 4 + (threadIdx.x >> 6);
    int l = threadIdx.x & 63;
    int jp = wid & 63;
    int po = wid >> 6;
    int j0 = jp * 2, j1 = j0 + 1;
    int pb = po * 8;

    float a0[8], a1[8];
    #pragma unroll
    for (int u = 0; u < 8; ++u) { a0[u] = 0.f; a1[u] = 0.f; }
    const float* wc0 = w1t + (size_t)j0 * 1536;
    const float* wc1 = w1t + (size_t)j1 * 1536;
    const float* fin[8]; const float* fde[8];
    #pragma unroll
    for (int u = 0; u < 8; ++u) {
        int p = pb + u;
        int i = p / NN; int n2 = p - i * NN; int bb = n2 / NE;
        fin[u] = inputs + ((size_t)bb * NE + i) * HH;
        fde[u] = denoise + (size_t)p * HH;
    }
    for (int it = 0; it < 24; ++it) {
        int t = it * 64 + l;
        float wv0 = wc0[t], wv1 = wc1[t];
        const bool isde = (it >= 12);
        int t2 = isde ? (t - HH) : t;
        #pragma unroll
        for (int u = 0; u < 8; ++u) {
            float fv = isde ? fde[u][t2] : fin[u][t2];
            a0[u] += fv * wv0;
            a1[u] += fv * wv1;
        }
    }
    #pragma unroll
    for (int u = 0; u < 8; ++u) {
        #pragma unroll
        for (int o = 32; o > 0; o >>= 1) {
            a0[u] += __shfl_xor(a0[u], o, 64);
            a1[u] += __shfl_xor(a1[u], o, 64);
        }
    }
    float bb0 = b1[j0], bb1 = b1[j1], w20 = W2[j0], w21 = W2[j1];
    if (l == 0) {
        #pragma unroll
        for (int u = 0; u < 8; ++u) {
            float v = fmaxf(a0[u] + bb0, 0.f) * w20 + fmaxf(a1[u] + bb1, 0.f) * w21;
            part[(size_t)(pb + u) * 64 + jp] = v;
        }
    }
}

// ---------------- K5c: deterministic reduce of part -> gsc ----------------
__global__ __launch_bounds__(256) void k_gatred(const float* __restrict__ part,
                                                float* __restrict__ gsc) {
    int p = blockIdx.x * 256 + threadIdx.x;
    if (p < NE * NN) {
        float s = 0.f;
        for (int jp = 0; jp < 64; ++jp) s += part[(size_t)p * 64 + jp];
        gsc[p] = s;   // b2 omitted: uniform shift, softmax-invariant
    }
}

// ---------------- K6: final combine (wave-parallel over i) ----------------
__global__ __launch_bounds__(256) void k_final(
    const float* __restrict__ inputs, const float* __restrict__ denoise,
    const float* __restrict__ gsc, const float* __restrict__ dsel,
    const float* __restrict__ inf_W, const float* __restrict__ inf_b,
    float* __restrict__ out)
{
    int b = blockIdx.x;
    int tid = threadIdx.x, wv = tid >> 6, l = tid & 63;
    __shared__ float sSp[NE];
    __shared__ float sWde[NE][NE];
    __shared__ float sLogi[NE][NCLS];
    if (tid == 0) {
        float m = -1e30f;
        for (int e2 = 0; e2 < NE; ++e2) m = fmaxf(m, dsel[b * NE + e2]);
        float s = 0.f;
        for (int e2 = 0; e2 < NE; ++e2) { float v = __expf(dsel[b * NE + e2] - m); sSp[e2] = v; s += v; }
        for (int e2 = 0; e2 < NE; ++e2) sSp[e2] /= s;
        for (int i = 0; i < NE; ++i) {
            float mm = -1e30f;
            for (int e2 = 0; e2 < NE; ++e2) mm = fmaxf(mm, gsc[i * NN + b * NE + e2]);
            float ss = 0.f;
            for (int e2 = 0; e2 < NE; ++e2) { float v = __expf(gsc[i * NN + b * NE + e2] - mm); sWde[i][e2] = v; ss += v; }
            for (int e2 = 0; e2 < NE; ++e2) sWde[i][e2] /= ss;
        }
    }
    __syncthreads();
    for (int i = wv; i < NE; i += 4) {
        float p0 = 0.f, p1 = 0.f, p2 = 0.f;
        for (int it = 0; it < 12; ++it) {
            int t = it * 64 + l;
            float f = inputs[((size_t)b * NE + i) * HH + t];
            p0 += f * inf_W[t * 3]; p1 += f * inf_W[t * 3 + 1]; p2 += f * inf_W[t * 3 + 2];
        }
        for (int it = 0; it < 12; ++it) {
            int h = it * 64 + l;
            float a = 0.f;
            #pragma unroll
            for (int e2 = 0; e2 < NE; ++e2)
                a += sWde[i][e2] * denoise[((size_t)i * NN + b * NE + e2) * HH + h];
            int t = HH + h;
            p0 += a * inf_W[t * 3]; p1 += a * inf_W[t * 3 + 1]; p2 += a * inf_W[t * 3 + 2];
        }
        #pragma unroll
        for (int o = 32; o > 0; o >>= 1) {
            p0 += __shfl_xor(p0, o, 64);
            p1 += __shfl_xor(p1, o, 64);
            p2 += __shfl_xor(p2, o, 64);
        }
        if (l == 0) {
            sLogi[i][0] = p0 + inf_b[0];
            sLogi[i][1] = p1 + inf_b[1];
            sLogi[i][2] = p2 + inf_b[2];
        }
    }
    __syncthreads();
    if (tid == 0) {
        float acc0 = 0.f, acc1 = 0.f, acc2 = 0.f;
        for (int i = 0; i < NE; ++i) {
            float mm = fmaxf(fmaxf(sLogi[i][0], sLogi[i][1]), sLogi[i][2]);
            float e0 = __expf(sLogi[i][0] - mm), e1 = __expf(sLogi[i][1] - mm), e2 = __expf(sLogi[i][2] - mm);
            float ss = e0 + e1 + e2;
            acc0 += sSp[i] * (e0 / ss);
            acc1 += sSp[i] * (e1 / ss);
            acc2 += sSp[i] * (e2 / ss);
        }
        out[b * NCLS + 0] = logf(acc0);
        out[b * NCLS + 1] = logf(acc1);
        out[b * NCLS + 2] = logf(acc2);
    }
}

extern "C" void kernel_launch(void* const* d_in, const int* in_sizes, int n_in,
                              void* d_out, int out_size, void* d_ws, size_t ws_size,
                              hipStream_t stream) {
    (void)in_sizes; (void)n_in; (void)out_size; (void)ws_size;
    const float* hid           = (const float*)d_in[0];
    const float* inputs        = (const float*)d_in[1];
    const float* mask_text     = (const float*)d_in[2];
    const float* mask_claim    = (const float*)d_in[3];
    const float* mask_evidence = (const float*)d_in[4];
    const float* W_att  = (const float*)d_in[5];
    const float* b_att  = (const float*)d_in[6];
    const float* W_sel  = (const float*)d_in[7];
    const float* b_sel  = (const float*)d_in[8];
    const float* gat_W1 = (const float*)d_in[9];
    const float* gat_b1 = (const float*)d_in[10];
    const float* gat_W2 = (const float*)d_in[11];
    const float* gat_b2 = (const float*)d_in[12];
    const float* inf_W  = (const float*)d_in[13];
    const float* inf_b  = (const float*)d_in[14];
    (void)gat_b2;

    short* hswz  = (short*)d_ws;                              // 15,728,640 B
    float* denoi = (float*)((char*)d_ws + 15728640);          // 307,200 f
    float* dsel  = denoi + 307200;                            // 80
    float* gsc   = dsel + 80;                                 // 400
    float* w1t   = gsc + 400;                                 // 196,608
    float* part  = w1t + 196608;                              // 25,600

    k_prep<<<NN, 256, 0, stream>>>(hid, hswz);
    k_w1t<<<(2 * HH * 128) / 256, 256, 0, stream>>>(gat_W1, w1t);
    k_simpool<<<NB * 25, 256, 0, stream>>>(hswz, hid, mask_text, mask_claim, mask_evidence,
                                           W_att, b_att, W_sel, b_sel, denoi, dsel);
    k_gat2<<<800, 256, 0, stream>>>(inputs, denoi, w1t, gat_b1, gat_W2, part);
    k_gatred<<<2, 256, 0, stream>>>(part, gsc);
    k_final<<<NB, 256, 0, stream>>>(inputs, denoi, gsc, dsel, inf_W, inf_b, (float*)d_out);
}

// Round 5
// 132.348 us; speedup vs baseline: 2.1857x; 1.4661x over previous
//
#include <hip/hip_runtime.h>
#include <math.h>

#define NB 16
#define NE 5
#define LL 128
#define HH 768
#define NK 21
#define NCLS 3
#define NN (NB*NE)   // 80

typedef float f32x4 __attribute__((ext_vector_type(4)));
typedef short s16x8 __attribute__((ext_vector_type(8)));

__device__ __forceinline__ short bf16rne(float f) {
    union { float f; unsigned u; } c; c.f = f;
    unsigned u = c.u;
    unsigned r = (u + 0x7FFFu + ((u >> 16) & 1u)) >> 16;
    return (short)r;
}
__device__ __forceinline__ float red16(float v) {
    v += __shfl_xor(v, 1, 64); v += __shfl_xor(v, 2, 64);
    v += __shfl_xor(v, 4, 64); v += __shfl_xor(v, 8, 64);
    return v;
}

// ------- K0: normalize + bf16 + MFMA-fragment swizzle (4 blocks per doc) -----
__global__ __launch_bounds__(256) void k_prep(const float* __restrict__ hid,
                                              short* __restrict__ hswz) {
    const int n = blockIdx.x >> 2, qtr = blockIdx.x & 3;
    const int tid = threadIdx.x, l = tid & 63, w = tid >> 6;
    __shared__ float sInv[32];
    #pragma unroll
    for (int rr = 0; rr < 8; ++rr) {
        const int lr = w * 8 + rr;             // local row 0..31
        const int row = qtr * 32 + lr;
        const float4* rp = reinterpret_cast<const float4*>(hid + ((size_t)n * LL + row) * HH);
        float4 a = rp[l], b = rp[l + 64], c = rp[l + 128];
        float ss = a.x*a.x + a.y*a.y + a.z*a.z + a.w*a.w
                 + b.x*b.x + b.y*b.y + b.z*b.z + b.w*b.w
                 + c.x*c.x + c.y*c.y + c.z*c.z + c.w*c.w;
        #pragma unroll
        for (int o = 32; o > 0; o >>= 1) ss += __shfl_xor(ss, o, 64);
        if (l == 0) sInv[lr] = 1.0f / fmaxf(sqrtf(ss), 1e-12f);
    }
    __syncthreads();
    const float* base = hid + (size_t)n * LL * HH;
    s16x8* dst = reinterpret_cast<s16x8*>(hswz) + (size_t)n * 12288;
    for (int li = tid; li < 3072; li += 256) {
        const int s = li >> 7, rem = li & 127;
        const int r = qtr * 128 + rem;
        const int ui = s * 512 + r;
        const int row = ((r >> 6) << 4) | (r & 15);
        const int kb = s * 32 + ((r >> 4) & 3) * 8;
        const float4* p = reinterpret_cast<const float4*>(base + (size_t)row * HH + kb);
        float4 v0 = p[0], v1 = p[1];
        const float inv = sInv[row - qtr * 32];
        s16x8 h;
        h[0] = bf16rne(v0.x * inv); h[1] = bf16rne(v0.y * inv);
        h[2] = bf16rne(v0.z * inv); h[3] = bf16rne(v0.w * inv);
        h[4] = bf16rne(v1.x * inv); h[5] = bf16rne(v1.y * inv);
        h[6] = bf16rne(v1.z * inv); h[7] = bf16rne(v1.w * inv);
        dst[ui] = h;
    }
}

// -------- epilogue row: chain kernel-pool -> logit accum, ALL named scalars --
__device__ __forceinline__ void epi_row(
    float s0, float s1, float s2, float s3, float s4, float s5, float s6, float s7,
    float mt0, float mt1, float mt2, float mt3, float mt4, float mt5, float mt6, float mt7,
    float me0, float me1, float me2, float me3, float me4, float me5, float me6, float me7,
    bool diag, float bAtt,
    const float* __restrict__ sWA, const float* __restrict__ sWS,
    const float* __restrict__ sCK,
    float* __restrict__ sAtt, float* __restrict__ sSelRow,
    const float* __restrict__ sMEq, const float* __restrict__ sMCq,
    int row, int lx)
{
    float pa = 0.f, ps = 0.f;
#define PK0(S, MT, ME) { float d_ = (S) - 1.0f; float g_ = exp2f(d_ * d_ * -721347.52f); \
                         pa += (MT) * g_; ps += (ME) * g_; }
    PK0(s0, mt0, me0) PK0(s1, mt1, me1) PK0(s2, mt2, me2) PK0(s3, mt3, me3)
    PK0(s4, mt4, me4) PK0(s5, mt5, me5) PK0(s6, mt6, me6) PK0(s7, mt7, me7)
#undef PK0
    pa = red16(pa);
    float lgt = fmaf(sWA[0], log2f(fmaxf(pa, 1e-10f)), bAtt);
    float rv = 0.f;
    if (diag) { ps = red16(ps); rv = sWS[0] * log2f(fmaxf(ps, 1e-10f)); }

    float u0,u1,u2,u3,u4,u5,u6,u7, v0,v1,v2,v3,v4,v5,v6,v7, t0,t1,t2,t3,t4,t5,t6,t7;
#define PKC(S, MT, ME, U, V, T) { float d_ = (S) - 0.95f; \
        float P_ = exp2f(fmaf(d_ * d_, -72.134752f, 32.0f)); \
        (T) = exp2f((S) * -14.4269504f); (U) = (MT) * P_; (V) = (ME) * P_; }
    PKC(s0, mt0, me0, u0, v0, t0) PKC(s1, mt1, me1, u1, v1, t1)
    PKC(s2, mt2, me2, u2, v2, t2) PKC(s3, mt3, me3, u3, v3, t3)
    PKC(s4, mt4, me4, u4, v4, t4) PKC(s5, mt5, me5, u5, v5, t5)
    PKC(s6, mt6, me6, u6, v6, t6) PKC(s7, mt7, me7, u7, v7, t7)
#undef PKC
    {
        float su = ((u0 + u1) + (u2 + u3)) + ((u4 + u5) + (u6 + u7));
        su = red16(su);
        lgt = fmaf(sWA[1], log2f(fmaxf(su * sCK[1], 1e-10f)), lgt);
        if (diag) {
            float sv = ((v0 + v1) + (v2 + v3)) + ((v4 + v5) + (v6 + v7));
            sv = red16(sv);
            rv = fmaf(sWS[1], log2f(fmaxf(sv * sCK[1], 1e-10f)), rv);
        }
    }
    for (int k = 2; k <= 20; ++k) {
        u0 *= t0; u1 *= t1; u2 *= t2; u3 *= t3;
        u4 *= t4; u5 *= t5; u6 *= t6; u7 *= t7;
        float su = ((u0 + u1) + (u2 + u3)) + ((u4 + u5) + (u6 + u7));
        su = red16(su);
        lgt = fmaf(sWA[k], log2f(fmaxf(su * sCK[k], 1e-10f)), lgt);
        if (diag) {
            v0 *= t0; v1 *= t1; v2 *= t2; v3 *= t3;
            v4 *= t4; v5 *= t5; v6 *= t6; v7 *= t7;
            float sv = ((v0 + v1) + (v2 + v3)) + ((v4 + v5) + (v6 + v7));
            sv = red16(sv);
            rv = fmaf(sWS[k], log2f(fmaxf(sv * sCK[k], 1e-10f)), rv);
        }
    }
    if (lx == 0) {
        sAtt[row] = (sMEq[row] == 0.0f) ? -10000.0f : lgt;
        if (diag) sSelRow[row] = sMCq[row] * rv;
    }
}

// ------- K2: 8-wave MFMA sim + in-register pooled logits + softmax + denoise -
__global__ __launch_bounds__(512, 4) void k_simpool(
    const short* __restrict__ hswz, const float* __restrict__ hid,
    const float* __restrict__ mask_text, const float* __restrict__ mask_claim,
    const float* __restrict__ mask_evidence,
    const float* __restrict__ W_att, const float* __restrict__ b_att,
    const float* __restrict__ W_sel, const float* __restrict__ b_sel,
    float* __restrict__ denoi, float* __restrict__ dsel)
{
    const int bid = blockIdx.x;
    const int b = bid & 15, pair = bid >> 4;
    const int e = pair / NE, ep = pair - e * NE;
    const int nq = b * NE + e, nd = b * NE + ep;
    const bool diag = (e == ep);
    const int tid = threadIdx.x, lane = tid & 63, w = tid >> 6;  // w: 0..7
    const int lx = lane & 15, lg = lane >> 4;

    __shared__ s16x8 sB[2][512];                       // 16 KB
    __shared__ float sMT[LL], sMEd[LL], sMEq[LL], sMCq[LL];
    __shared__ float sAtt[LL], sSelRow[LL];
    __shared__ float sWA[NK], sWS[NK], sCK[NK];

    if (tid < LL) {
        sMT[tid]  = mask_text[nd * LL + tid];
        sMEd[tid] = mask_evidence[nd * LL + tid];
        sMEq[tid] = mask_evidence[nq * LL + tid];
        sMCq[tid] = mask_claim[nq * LL + tid];
    } else if (tid >= 128 && tid < 128 + NK) {
        sWA[tid - 128] = W_att[tid - 128] * 0.69314718f;
    } else if (tid >= 160 && tid < 160 + NK) {
        sWS[tid - 160] = W_sel[tid - 160] * 0.69314718f;
    } else if (tid >= 192 && tid < 212) {
        const int k = tid - 191;                        // 1..20
        const float kk = (float)(k - 1);
        sCK[k] = exp2f(fmaf(kk, 13.7056029f, fmaf(kk * kk, -0.72134752f, -32.0f)));
    }

    const s16x8* gA = reinterpret_cast<const s16x8*>(hswz) + (size_t)nq * 12288;
    const s16x8* gB = reinterpret_cast<const s16x8*>(hswz) + (size_t)nd * 12288;

    sB[0][tid] = gB[tid];
    s16x8 aC = gA[w * 64 + lane];

    f32x4 acc[8];
    #pragma unroll
    for (int nj = 0; nj < 8; ++nj) acc[nj] = (f32x4){0.f, 0.f, 0.f, 0.f};

    __syncthreads();

    for (int s = 0; s < 24; ++s) {
        const int cur = s & 1;
        s16x8 nB, aN;
        if (s < 23) {
            nB = gB[(s + 1) * 512 + tid];
            aN = gA[(s + 1) * 512 + w * 64 + lane];
        }
        #pragma unroll
        for (int nj = 0; nj < 8; ++nj) {
            s16x8 bf = sB[cur][nj * 64 + lane];
            acc[nj] = __builtin_amdgcn_mfma_f32_16x16x32_bf16(aC, bf, acc[nj], 0, 0, 0);
        }
        if (s < 23) {
            sB[1 - cur][tid] = nB;
            aC = aN;
        }
        __syncthreads();
    }

    // ---- epilogue: 4 rows/thread ----
    const float bAtt = b_att[0];
    const float mt0 = sMT[lx],       mt1 = sMT[16 + lx],  mt2 = sMT[32 + lx],  mt3 = sMT[48 + lx];
    const float mt4 = sMT[64 + lx],  mt5 = sMT[80 + lx],  mt6 = sMT[96 + lx],  mt7 = sMT[112 + lx];
    float me0 = 0.f, me1 = 0.f, me2 = 0.f, me3 = 0.f, me4 = 0.f, me5 = 0.f, me6 = 0.f, me7 = 0.f;
    if (diag) {
        me0 = sMEd[lx];      me1 = sMEd[16 + lx]; me2 = sMEd[32 + lx];  me3 = sMEd[48 + lx];
        me4 = sMEd[64 + lx]; me5 = sMEd[80 + lx]; me6 = sMEd[96 + lx];  me7 = sMEd[112 + lx];
    }
    const int rb = w * 16 + lg * 4;
#define EPI(R) epi_row(acc[0][R], acc[1][R], acc[2][R], acc[3][R], \
                       acc[4][R], acc[5][R], acc[6][R], acc[7][R], \
                       mt0, mt1, mt2, mt3, mt4, mt5, mt6, mt7, \
                       me0, me1, me2, me3, me4, me5, me6, me7, \
                       diag, bAtt, sWA, sWS, sCK, sAtt, sSelRow, sMEq, sMCq, \
                       rb + (R), lx);
    EPI(0) EPI(1) EPI(2) EPI(3)
#undef EPI
    __syncthreads();

    // ---- softmax over q (wave 0) + dsel (wave 1) ----
    if (tid < 64) {
        float a0 = sAtt[tid], a1 = sAtt[tid + 64];
        float m = fmaxf(a0, a1);
        #pragma unroll
        for (int o = 32; o > 0; o >>= 1) m = fmaxf(m, __shfl_xor(m, o, 64));
        float e0 = __expf(a0 - m), e1 = __expf(a1 - m);
        float ssum = e0 + e1;
        #pragma unroll
        for (int o = 32; o > 0; o >>= 1) ssum += __shfl_xor(ssum, o, 64);
        float inv = 1.0f / ssum;
        sAtt[tid] = e0 * inv; sAtt[tid + 64] = e1 * inv;
    } else if (diag && tid < 128) {
        const int l2 = tid - 64;
        float su = sSelRow[l2] + sSelRow[l2 + 64];
        float ms = sMCq[l2] + sMCq[l2 + 64];
        #pragma unroll
        for (int o = 32; o > 0; o >>= 1) {
            su += __shfl_xor(su, o, 64);
            ms += __shfl_xor(ms, o, 64);
        }
        if (l2 == 0) dsel[nq] = b_sel[0] + 0.01f * su / (ms + 1e-10f);
    }
    __syncthreads();

    // ---- denoise: att^T x hid[nq] ----
    const float* hq = hid + (size_t)nq * LL * HH;
    for (int h = tid; h < HH; h += 512) {
        float a = 0.f;
        for (int q = 0; q < LL; ++q) a += sAtt[q] * hq[(size_t)q * HH + h];
        denoi[((size_t)ep * NN + nq) * HH + h] = a;
    }
}

// ---------------- K5a: transpose W1 -> W1T[128][1536] ----------------
__global__ __launch_bounds__(256) void k_w1t(const float* __restrict__ W1,
                                             float* __restrict__ w1t) {
    int o = blockIdx.x * 256 + threadIdx.x;
    int j = o / 1536, t = o - j * 1536;
    w1t[o] = W1[(size_t)t * 128 + j];
}

// ---------------- K5b: GAT gate — one wave per (j-pair, 8 p's) --------------
__global__ __launch_bounds__(256) void k_gat2(
    const float* __restrict__ inputs, const float* __restrict__ denoise,
    const float* __restrict__ w1t, const float* __restrict__ b1,
    const float* __restrict__ W2, float* __restrict__ part)
{
    int wid = blockIdx.x * 4 + (threadIdx.x >> 6);
    int l = threadIdx.x & 63;
    int jp = wid & 63;
    int po = wid >> 6;
    int j0 = jp * 2, j1 = j0 + 1;
    int pb = po * 8;

    float a0[8], a1[8];
    #pragma unroll
    for (int u = 0; u < 8; ++u) { a0[u] = 0.f; a1[u] = 0.f; }
    const float* wc0 = w1t + (size_t)j0 * 1536;
    const float* wc1 = w1t + (size_t)j1 * 1536;
    const float* fin[8]; const float* fde[8];
    #pragma unroll
    for (int u = 0; u < 8; ++u) {
        int p = pb + u;
        int i = p / NN; int n2 = p - i * NN; int bb = n2 / NE;
        fin[u] = inputs + ((size_t)bb * NE + i) * HH;
        fde[u] = denoise + (size_t)p * HH;
    }
    for (int it = 0; it < 24; ++it) {
        int t = it * 64 + l;
        float wv0 = wc0[t], wv1 = wc1[t];
        const bool isde = (it >= 12);
        int t2 = isde ? (t - HH) : t;
        #pragma unroll
        for (int u = 0; u < 8; ++u) {
            float fv = isde ? fde[u][t2] : fin[u][t2];
            a0[u] += fv * wv0;
            a1[u] += fv * wv1;
        }
    }
    #pragma unroll
    for (int u = 0; u < 8; ++u) {
        #pragma unroll
        for (int o = 32; o > 0; o >>= 1) {
            a0[u] += __shfl_xor(a0[u], o, 64);
            a1[u] += __shfl_xor(a1[u], o, 64);
        }
    }
    float bb0 = b1[j0], bb1 = b1[j1], w20 = W2[j0], w21 = W2[j1];
    if (l == 0) {
        #pragma unroll
        for (int u = 0; u < 8; ++u) {
            float v = fmaxf(a0[u] + bb0, 0.f) * w20 + fmaxf(a1[u] + bb1, 0.f) * w21;
            part[(size_t)(pb + u) * 64 + jp] = v;
        }
    }
}

// ---------------- K5c: deterministic reduce of part -> gsc ----------------
__global__ __launch_bounds__(256) void k_gatred(const float* __restrict__ part,
                                                float* __restrict__ gsc) {
    int p = blockIdx.x * 256 + threadIdx.x;
    if (p < NE * NN) {
        float s = 0.f;
        for (int jp = 0; jp < 64; ++jp) s += part[(size_t)p * 64 + jp];
        gsc[p] = s;   // b2 omitted: uniform shift, softmax-invariant
    }
}

// ---------------- K6a: per-(b,i) class logits ----------------
__global__ __launch_bounds__(256) void k_logits(
    const float* __restrict__ inputs, const float* __restrict__ denoise,
    const float* __restrict__ gsc, const float* __restrict__ inf_W,
    const float* __restrict__ inf_b, float* __restrict__ logi)
{
    const int bid = blockIdx.x;        // b*NE + i
    const int b = bid / NE, i = bid - b * NE;
    const int tid = threadIdx.x, l = tid & 63, wv = tid >> 6;
    // gat softmax weights (redundant per-thread, 5 cached loads)
    float g0 = gsc[i * NN + b * NE + 0], g1 = gsc[i * NN + b * NE + 1];
    float g2 = gsc[i * NN + b * NE + 2], g3 = gsc[i * NN + b * NE + 3];
    float g4 = gsc[i * NN + b * NE + 4];
    float mm = fmaxf(fmaxf(fmaxf(g0, g1), fmaxf(g2, g3)), g4);
    float w0 = __expf(g0 - mm), w1 = __expf(g1 - mm), w2 = __expf(g2 - mm);
    float w3 = __expf(g3 - mm), w4 = __expf(g4 - mm);
    float inv = 1.0f / (w0 + w1 + w2 + w3 + w4);
    w0 *= inv; w1 *= inv; w2 *= inv; w3 *= inv; w4 *= inv;

    float p0 = 0.f, p1 = 0.f, p2 = 0.f;
    const float* xin = inputs + ((size_t)b * NE + i) * HH;
    const float* de = denoise + ((size_t)i * NN + b * NE) * HH;
    #pragma unroll
    for (int it = 0; it < 3; ++it) {
        int t = it * 256 + tid;
        float f = xin[t];
        p0 += f * inf_W[t * 3]; p1 += f * inf_W[t * 3 + 1]; p2 += f * inf_W[t * 3 + 2];
    }
    #pragma unroll
    for (int it = 0; it < 3; ++it) {
        int h = it * 256 + tid;
        float a = w0 * de[h] + w1 * de[HH + h] + w2 * de[2 * HH + h]
                + w3 * de[3 * HH + h] + w4 * de[4 * HH + h];
        int t = HH + h;
        p0 += a * inf_W[t * 3]; p1 += a * inf_W[t * 3 + 1]; p2 += a * inf_W[t * 3 + 2];
    }
    #pragma unroll
    for (int o = 32; o > 0; o >>= 1) {
        p0 += __shfl_xor(p0, o, 64);
        p1 += __shfl_xor(p1, o, 64);
        p2 += __shfl_xor(p2, o, 64);
    }
    __shared__ float red[4][NCLS];
    if (l == 0) { red[wv][0] = p0; red[wv][1] = p1; red[wv][2] = p2; }
    __syncthreads();
    if (tid < NCLS) {
        logi[bid * NCLS + tid] = red[0][tid] + red[1][tid] + red[2][tid] + red[3][tid]
                               + inf_b[tid];
    }
}

// ---------------- K6b: combine (16 threads) ----------------
__global__ __launch_bounds__(64) void k_combine(
    const float* __restrict__ dsel, const float* __restrict__ logi,
    float* __restrict__ out)
{
    const int b = threadIdx.x;
    if (b >= NB) return;
    float d0 = dsel[b * NE], d1 = dsel[b * NE + 1], d2 = dsel[b * NE + 2];
    float d3 = dsel[b * NE + 3], d4 = dsel[b * NE + 4];
    float m = fmaxf(fmaxf(fmaxf(d0, d1), fmaxf(d2, d3)), d4);
    float s0 = __expf(d0 - m), s1 = __expf(d1 - m), s2 = __expf(d2 - m);
    float s3 = __expf(d3 - m), s4 = __expf(d4 - m);
    float sinv = 1.0f / (s0 + s1 + s2 + s3 + s4);
    float sp0 = s0 * sinv, sp1 = s1 * sinv, sp2 = s2 * sinv, sp3 = s3 * sinv, sp4 = s4 * sinv;
    float acc0 = 0.f, acc1 = 0.f, acc2 = 0.f;
#define CMB(I, SP) { \
        float l0 = logi[(b * NE + (I)) * NCLS], l1 = logi[(b * NE + (I)) * NCLS + 1], \
              l2 = logi[(b * NE + (I)) * NCLS + 2]; \
        float mm = fmaxf(fmaxf(l0, l1), l2); \
        float e0 = __expf(l0 - mm), e1 = __expf(l1 - mm), e2 = __expf(l2 - mm); \
        float si = 1.0f / (e0 + e1 + e2); \
        acc0 += (SP) * e0 * si; acc1 += (SP) * e1 * si; acc2 += (SP) * e2 * si; }
    CMB(0, sp0) CMB(1, sp1) CMB(2, sp2) CMB(3, sp3) CMB(4, sp4)
#undef CMB
    out[b * NCLS + 0] = logf(acc0);
    out[b * NCLS + 1] = logf(acc1);
    out[b * NCLS + 2] = logf(acc2);
}

extern "C" void kernel_launch(void* const* d_in, const int* in_sizes, int n_in,
                              void* d_out, int out_size, void* d_ws, size_t ws_size,
                              hipStream_t stream) {
    (void)in_sizes; (void)n_in; (void)out_size; (void)ws_size;
    const float* hid           = (const float*)d_in[0];
    const float* inputs        = (const float*)d_in[1];
    const float* mask_text     = (const float*)d_in[2];
    const float* mask_claim    = (const float*)d_in[3];
    const float* mask_evidence = (const float*)d_in[4];
    const float* W_att  = (const float*)d_in[5];
    const float* b_att  = (const float*)d_in[6];
    const float* W_sel  = (const float*)d_in[7];
    const float* b_sel  = (const float*)d_in[8];
    const float* gat_W1 = (const float*)d_in[9];
    const float* gat_b1 = (const float*)d_in[10];
    const float* gat_W2 = (const float*)d_in[11];
    const float* gat_b2 = (const float*)d_in[12];
    const float* inf_W  = (const float*)d_in[13];
    const float* inf_b  = (const float*)d_in[14];
    (void)gat_b2;

    short* hswz  = (short*)d_ws;                              // 15,728,640 B
    float* denoi = (float*)((char*)d_ws + 15728640);          // 307,200 f
    float* dsel  = denoi + 307200;                            // 80
    float* gsc   = dsel + 80;                                 // 400
    float* w1t   = gsc + 400;                                 // 196,608
    float* part  = w1t + 196608;                              // 25,600
    float* logi  = part + 25600;                              // 240

    k_prep<<<NN * 4, 256, 0, stream>>>(hid, hswz);
    k_w1t<<<(2 * HH * 128) / 256, 256, 0, stream>>>(gat_W1, w1t);
    k_simpool<<<NB * 25, 512, 0, stream>>>(hswz, hid, mask_text, mask_claim, mask_evidence,
                                           W_att, b_att, W_sel, b_sel, denoi, dsel);
    k_gat2<<<800, 256, 0, stream>>>(inputs, denoi, w1t, gat_b1, gat_W2, part);
    k_gatred<<<2, 256, 0, stream>>>(part, gsc);
    k_logits<<<NN, 256, 0, stream>>>(inputs, denoi, gsc, inf_W, inf_b, logi);
    k_combine<<<1, 64, 0, stream>>>(dsel, logi, (float*)d_out);
}